// Round 1
// baseline (662.939 us; speedup 1.0000x reference)
//
#include <hip/hip_runtime.h>
#include <hip/hip_bf16.h>
#include <math.h>

// Problem constants (fixed by the reference)
#define N_NODES 10000
#define N_EDGES 160000
#define BATCH   4096
#define DIM     512
#define HID     256

// ---------------------------------------------------------------------------
// small utility kernels
// ---------------------------------------------------------------------------
__global__ void zero2_kernel(int* a, int* b, int n) {
    int i = blockIdx.x * blockDim.x + threadIdx.x;
    if (i < n) { a[i] = 0; b[i] = 0; }
}

__global__ void count_deg_kernel(const int* __restrict__ dst, int* __restrict__ cnt, int E) {
    int e = blockIdx.x * blockDim.x + threadIdx.x;
    if (e < E) atomicAdd(&cnt[dst[e]], 1);
}

__global__ void dinv_kernel(const int* __restrict__ cnt, float* __restrict__ dinv, int n) {
    int i = blockIdx.x * blockDim.x + threadIdx.x;
    if (i < n) dinv[i] = rsqrtf((float)(1 + cnt[i]));   // deg = 1 (self loop) + in-degree
}

// single-block exclusive scan of cnt[0..n) -> offs[0..n], offs[n] = total
__global__ void scan_offsets_kernel(const int* __restrict__ cnt, int* __restrict__ offs, int n) {
    __shared__ int buf[1024];
    __shared__ int base_s;
    if (threadIdx.x == 0) base_s = 0;
    __syncthreads();
    for (int start = 0; start < n; start += 1024) {
        int i = start + (int)threadIdx.x;
        int v = (i < n) ? cnt[i] : 0;
        buf[threadIdx.x] = v;
        __syncthreads();
        for (int off = 1; off < 1024; off <<= 1) {
            int add = (threadIdx.x >= (unsigned)off) ? buf[threadIdx.x - off] : 0;
            __syncthreads();
            buf[threadIdx.x] += add;
            __syncthreads();
        }
        if (i < n) offs[i] = base_s + buf[threadIdx.x] - v;   // exclusive
        __syncthreads();
        if (threadIdx.x == 0) base_s += buf[1023];
        __syncthreads();
    }
    if (threadIdx.x == 0) offs[n] = base_s;
}

__global__ void fill_csr_kernel(const int* __restrict__ dst, const int* __restrict__ offs,
                                int* __restrict__ cursor, int* __restrict__ csr, int E) {
    int e = blockIdx.x * blockDim.x + threadIdx.x;
    if (e < E) {
        int d = dst[e];
        int p = offs[d] + atomicAdd(&cursor[d], 1);
        csr[p] = e;
    }
}

// ---------------------------------------------------------------------------
// GCN aggregation: out[n] = sum_{e:dst=n} dinv[src]*dinv[n]*xw[src] + dinv[n]^2*xw[n] + b
// layer1: 256 channels, relu.  layer2: 512 channels, no relu.
// ---------------------------------------------------------------------------
__global__ __launch_bounds__(256) void agg1_kernel(const float* __restrict__ xw,
        const float* __restrict__ dinv, const int* __restrict__ src,
        const int* __restrict__ offs, const int* __restrict__ csr,
        const float* __restrict__ bias, float* __restrict__ out) {
    int n = blockIdx.x;
    int c = threadIdx.x;          // 0..255
    float di = dinv[n];
    float acc = di * di * xw[(size_t)n * HID + c];
    int s0 = offs[n], s1 = offs[n + 1];
    for (int i = s0; i < s1; ++i) {
        int e  = csr[i];
        int sr = src[e];
        acc += di * dinv[sr] * xw[(size_t)sr * HID + c];
    }
    acc += bias[c];
    out[(size_t)n * HID + c] = fmaxf(acc, 0.0f);
}

__global__ __launch_bounds__(256) void agg2_kernel(const float* __restrict__ xw,
        const float* __restrict__ dinv, const int* __restrict__ src,
        const int* __restrict__ offs, const int* __restrict__ csr,
        const float* __restrict__ bias, float* __restrict__ out) {
    int n = blockIdx.x;
    int c = threadIdx.x;          // handles c and c+256
    float di = dinv[n];
    float d2 = di * di;
    float acc0 = d2 * xw[(size_t)n * DIM + c];
    float acc1 = d2 * xw[(size_t)n * DIM + c + 256];
    int s0 = offs[n], s1 = offs[n + 1];
    for (int i = s0; i < s1; ++i) {
        int e  = csr[i];
        int sr = src[e];
        float w = di * dinv[sr];
        acc0 += w * xw[(size_t)sr * DIM + c];
        acc1 += w * xw[(size_t)sr * DIM + c + 256];
    }
    out[(size_t)n * DIM + c]       = acc0 + bias[c];
    out[(size_t)n * DIM + c + 256] = acc1 + bias[c + 256];
}

// ---------------------------------------------------------------------------
// Dense NN GEMM: C[M,N] = A[M,K] @ B[K,N] (+bias, relu optional)
// tile 128x64, BK=16, 256 threads, 8x4 micro-tile per thread
// ---------------------------------------------------------------------------
#define BM 128
#define BN 64
#define BK 16

template <bool BIAS_RELU>
__global__ __launch_bounds__(256) void gemm_nn_kernel(const float* __restrict__ A,
        const float* __restrict__ Bm, const float* __restrict__ bias,
        float* __restrict__ C, int M, int N, int K) {
    __shared__ float As[BK][BM + 4];
    __shared__ float Bs[BK][BN + 4];
    int t   = threadIdx.x;
    int rt  = blockIdx.y, ct = blockIdx.x;
    int row0 = rt * BM, col0 = ct * BN;
    int a_row = t >> 2;              // 0..63
    int a_k4  = (t & 3) * 4;         // 0,4,8,12
    int b_k   = t >> 4;              // 0..15
    int b_n   = (t & 15) * 4;        // 0..60
    int tx = t & 15, ty = t >> 4;

    float acc[8][4];
#pragma unroll
    for (int i = 0; i < 8; ++i)
#pragma unroll
        for (int j = 0; j < 4; ++j) acc[i][j] = 0.0f;

    for (int k0 = 0; k0 < K; k0 += BK) {
        int r1 = row0 + a_row;       if (r1 > M - 1) r1 = M - 1;
        int r2 = row0 + a_row + 64;  if (r2 > M - 1) r2 = M - 1;
        float4 v1 = *(const float4*)&A[(size_t)r1 * K + k0 + a_k4];
        float4 v2 = *(const float4*)&A[(size_t)r2 * K + k0 + a_k4];
        As[a_k4 + 0][a_row] = v1.x;  As[a_k4 + 1][a_row] = v1.y;
        As[a_k4 + 2][a_row] = v1.z;  As[a_k4 + 3][a_row] = v1.w;
        As[a_k4 + 0][a_row + 64] = v2.x;  As[a_k4 + 1][a_row + 64] = v2.y;
        As[a_k4 + 2][a_row + 64] = v2.z;  As[a_k4 + 3][a_row + 64] = v2.w;
        float4 bv = *(const float4*)&Bm[(size_t)(k0 + b_k) * N + col0 + b_n];
        *(float4*)&Bs[b_k][b_n] = bv;
        __syncthreads();
#pragma unroll
        for (int k = 0; k < BK; ++k) {
            float4 a0 = *(const float4*)&As[k][ty * 8];
            float4 a1 = *(const float4*)&As[k][ty * 8 + 4];
            float4 b0 = *(const float4*)&Bs[k][tx * 4];
            float av[8] = {a0.x, a0.y, a0.z, a0.w, a1.x, a1.y, a1.z, a1.w};
            float bvv[4] = {b0.x, b0.y, b0.z, b0.w};
#pragma unroll
            for (int i = 0; i < 8; ++i)
#pragma unroll
                for (int j = 0; j < 4; ++j) acc[i][j] = fmaf(av[i], bvv[j], acc[i][j]);
        }
        __syncthreads();
    }

    float4 bb = make_float4(0.f, 0.f, 0.f, 0.f);
    if (BIAS_RELU) bb = *(const float4*)&bias[col0 + tx * 4];
#pragma unroll
    for (int i = 0; i < 8; ++i) {
        int r = row0 + ty * 8 + i;
        if (r < M) {
            float4 v = make_float4(acc[i][0], acc[i][1], acc[i][2], acc[i][3]);
            if (BIAS_RELU) {
                v.x = fmaxf(v.x + bb.x, 0.f); v.y = fmaxf(v.y + bb.y, 0.f);
                v.z = fmaxf(v.z + bb.z, 0.f); v.w = fmaxf(v.w + bb.w, 0.f);
            }
            *(float4*)&C[(size_t)r * N + col0 + tx * 4] = v;
        }
    }
}

// ---------------------------------------------------------------------------
// logits = gout[label] @ img^T, fused per-row online (max, sumexp) per col-tile
// tile 128x128, BK=16, 256 threads, 8x8 micro
// ---------------------------------------------------------------------------
#define LBM 128
#define LBN 128

__global__ __launch_bounds__(256) void logits_kernel(const float* __restrict__ gout,
        const int* __restrict__ label, const float* __restrict__ img,
        float* __restrict__ pmax, float* __restrict__ psum, float* __restrict__ diagv) {
    __shared__ float As[BK][LBM + 4];
    __shared__ float Bs[BK][LBN + 4];
    __shared__ int lbl[LBM];
    int t  = threadIdx.x;
    int ct = blockIdx.x, rt = blockIdx.y;
    if (t < 128) lbl[t] = label[rt * 128 + t];
    __syncthreads();
    int a_row = t >> 2;          // 0..63
    int a_k4  = (t & 3) * 4;
    int tx = t & 15, ty = t >> 4;

    float acc[8][8];
#pragma unroll
    for (int i = 0; i < 8; ++i)
#pragma unroll
        for (int j = 0; j < 8; ++j) acc[i][j] = 0.0f;

    for (int k0 = 0; k0 < DIM; k0 += BK) {
        // A tile: rows gathered through label
        float4 v1 = *(const float4*)&gout[(size_t)lbl[a_row]      * DIM + k0 + a_k4];
        float4 v2 = *(const float4*)&gout[(size_t)lbl[a_row + 64] * DIM + k0 + a_k4];
        As[a_k4 + 0][a_row] = v1.x;  As[a_k4 + 1][a_row] = v1.y;
        As[a_k4 + 2][a_row] = v1.z;  As[a_k4 + 3][a_row] = v1.w;
        As[a_k4 + 0][a_row + 64] = v2.x;  As[a_k4 + 1][a_row + 64] = v2.y;
        As[a_k4 + 2][a_row + 64] = v2.z;  As[a_k4 + 3][a_row + 64] = v2.w;
        // B tile: img rows (NT gemm: both K-contiguous)
        float4 w1 = *(const float4*)&img[(size_t)(ct * 128 + a_row)      * DIM + k0 + a_k4];
        float4 w2 = *(const float4*)&img[(size_t)(ct * 128 + a_row + 64) * DIM + k0 + a_k4];
        Bs[a_k4 + 0][a_row] = w1.x;  Bs[a_k4 + 1][a_row] = w1.y;
        Bs[a_k4 + 2][a_row] = w1.z;  Bs[a_k4 + 3][a_row] = w1.w;
        Bs[a_k4 + 0][a_row + 64] = w2.x;  Bs[a_k4 + 1][a_row + 64] = w2.y;
        Bs[a_k4 + 2][a_row + 64] = w2.z;  Bs[a_k4 + 3][a_row + 64] = w2.w;
        __syncthreads();
#pragma unroll
        for (int k = 0; k < BK; ++k) {
            float4 a0 = *(const float4*)&As[k][ty * 8];
            float4 a1 = *(const float4*)&As[k][ty * 8 + 4];
            float4 b0 = *(const float4*)&Bs[k][tx * 8];
            float4 b1 = *(const float4*)&Bs[k][tx * 8 + 4];
            float av[8] = {a0.x, a0.y, a0.z, a0.w, a1.x, a1.y, a1.z, a1.w};
            float bv[8] = {b0.x, b0.y, b0.z, b0.w, b1.x, b1.y, b1.z, b1.w};
#pragma unroll
            for (int i = 0; i < 8; ++i)
#pragma unroll
                for (int j = 0; j < 8; ++j) acc[i][j] = fmaf(av[i], bv[j], acc[i][j]);
        }
        __syncthreads();
    }

    // diagonal elements (needed for -label_i * logsoftmax[i,i])
    if (rt == ct && tx == ty) {
#pragma unroll
        for (int i = 0; i < 8; ++i) diagv[rt * 128 + ty * 8 + i] = acc[i][i];
    }

    // per-row online softmax partials over this 128-col tile
#pragma unroll
    for (int i = 0; i < 8; ++i) {
        float m = acc[i][0];
#pragma unroll
        for (int j = 1; j < 8; ++j) m = fmaxf(m, acc[i][j]);
        float s = 0.0f;
#pragma unroll
        for (int j = 0; j < 8; ++j) s += expf(acc[i][j] - m);
        // combine across the 16 lanes sharing ty (lanes form aligned 16-groups)
#pragma unroll
        for (int d = 1; d < 16; d <<= 1) {
            float mo = __shfl_xor(m, d, 64);
            float so = __shfl_xor(s, d, 64);
            float mn = fmaxf(m, mo);
            s = s * expf(m - mn) + so * expf(mo - mn);
            m = mn;
        }
        if (tx == 0) {
            int row = rt * 128 + ty * 8 + i;
            pmax[(size_t)row * 32 + ct] = m;
            psum[(size_t)row * 32 + ct] = s;
        }
    }
}

// combine 32 col-tile partials per row -> per-row loss term
__global__ __launch_bounds__(256) void row_finalize_kernel(const float* __restrict__ pmax,
        const float* __restrict__ psum, const float* __restrict__ diagv,
        const int* __restrict__ label, float* __restrict__ terms) {
    int gid  = blockIdx.x * blockDim.x + threadIdx.x;
    int row  = gid >> 6;
    int lane = threadIdx.x & 63;
    if (row >= BATCH) return;
    float m = -INFINITY, s = 0.0f;
    if (lane < 32) { m = pmax[(size_t)row * 32 + lane]; s = psum[(size_t)row * 32 + lane]; }
#pragma unroll
    for (int d = 1; d < 32; d <<= 1) {
        float mo = __shfl_xor(m, d, 64);
        float so = __shfl_xor(s, d, 64);
        float mn = fmaxf(m, mo);
        s = s * expf(m - mn) + so * expf(mo - mn);
        m = mn;
    }
    if (lane == 0) {
        float lse = m + logf(s);
        terms[row] = -(float)label[row] * (diagv[row] - lse);
    }
}

__global__ __launch_bounds__(256) void final_sum_kernel(const float* __restrict__ terms,
                                                        float* __restrict__ out) {
    __shared__ float red[256];
    float s = 0.0f;
    for (int i = threadIdx.x; i < BATCH; i += 256) s += terms[i];
    red[threadIdx.x] = s;
    __syncthreads();
    for (int w = 128; w > 0; w >>= 1) {
        if (threadIdx.x < (unsigned)w) red[threadIdx.x] += red[threadIdx.x + w];
        __syncthreads();
    }
    // contrastive mean + triplet loss (identically 1.0: d_ap==d_an, relu(margin)=1)
    if (threadIdx.x == 0) out[0] = red[0] / (float)BATCH + 1.0f;
}

// ---------------------------------------------------------------------------
extern "C" void kernel_launch(void* const* d_in, const int* in_sizes, int n_in,
                              void* d_out, int out_size, void* d_ws, size_t ws_size,
                              hipStream_t stream) {
    const float* image   = (const float*)d_in[0];
    const float* x_nodes = (const float*)d_in[1];
    const int*   edge    = (const int*)d_in[2];
    const int*   label   = (const int*)d_in[3];
    const float* W_img1  = (const float*)d_in[4];
    const float* b_img1  = (const float*)d_in[5];
    const float* W_img2  = (const float*)d_in[6];
    const float* b_img2  = (const float*)d_in[7];
    const float* W_g1    = (const float*)d_in[8];
    const float* b_g1    = (const float*)d_in[9];
    const float* W_g2    = (const float*)d_in[10];
    const float* b_g2    = (const float*)d_in[11];
    const int* src = edge;              // edge_index[0]
    const int* dst = edge + N_EDGES;    // edge_index[1]

    // workspace carve-up (256B aligned regions)
    char* ws = (char*)d_ws;
    size_t off = 0;
    auto alloc = [&](size_t bytes) { size_t r = off; off = (off + bytes + 255) & ~(size_t)255; return r; };
    float* dinv   = (float*)(ws + alloc(N_NODES * 4));
    int*   cnt    = (int*)  (ws + alloc(N_NODES * 4));
    int*   offs   = (int*)  (ws + alloc((N_NODES + 1) * 4));
    int*   cursor = (int*)  (ws + alloc(N_NODES * 4));
    int*   csr    = (int*)  (ws + alloc(N_EDGES * 4));
    float* xw1    = (float*)(ws + alloc((size_t)N_NODES * HID * 4));
    float* h      = (float*)(ws + alloc((size_t)N_NODES * HID * 4));
    float* xw2    = (float*)(ws + alloc((size_t)N_NODES * DIM * 4));
    float* gout   = (float*)(ws + alloc((size_t)N_NODES * DIM * 4));
    float* himg   = (float*)(ws + alloc((size_t)BATCH * HID * 4));
    float* img    = (float*)(ws + alloc((size_t)BATCH * DIM * 4));
    float* pmax   = (float*)(ws + alloc((size_t)BATCH * 32 * 4));
    float* psum   = (float*)(ws + alloc((size_t)BATCH * 32 * 4));
    float* diagv  = (float*)(ws + alloc(BATCH * 4));
    float* terms  = (float*)(ws + alloc(BATCH * 4));

    // graph build: CSR by dst + symmetric-norm coefficients
    zero2_kernel<<<(N_NODES + 255) / 256, 256, 0, stream>>>(cnt, cursor, N_NODES);
    count_deg_kernel<<<(N_EDGES + 255) / 256, 256, 0, stream>>>(dst, cnt, N_EDGES);
    dinv_kernel<<<(N_NODES + 255) / 256, 256, 0, stream>>>(cnt, dinv, N_NODES);
    scan_offsets_kernel<<<1, 1024, 0, stream>>>(cnt, offs, N_NODES);
    fill_csr_kernel<<<(N_EDGES + 255) / 256, 256, 0, stream>>>(dst, offs, cursor, csr, N_EDGES);

    // GCN layer 1: xw1 = x_nodes @ W_g1 ; h = relu(agg + self + b)
    gemm_nn_kernel<false><<<dim3(HID / BN, (N_NODES + BM - 1) / BM), 256, 0, stream>>>(
        x_nodes, W_g1, nullptr, xw1, N_NODES, HID, DIM);
    agg1_kernel<<<N_NODES, 256, 0, stream>>>(xw1, dinv, src, offs, csr, b_g1, h);

    // GCN layer 2: xw2 = h @ W_g2 ; gout = agg + self + b
    gemm_nn_kernel<false><<<dim3(DIM / BN, (N_NODES + BM - 1) / BM), 256, 0, stream>>>(
        h, W_g2, nullptr, xw2, N_NODES, DIM, HID);
    agg2_kernel<<<N_NODES, 256, 0, stream>>>(xw2, dinv, src, offs, csr, b_g2, gout);

    // image MLP: himg = relu(image@W1+b1) ; img = relu(himg@W2+b2)
    gemm_nn_kernel<true><<<dim3(HID / BN, BATCH / BM), 256, 0, stream>>>(
        image, W_img1, b_img1, himg, BATCH, HID, DIM);
    gemm_nn_kernel<true><<<dim3(DIM / BN, BATCH / BM), 256, 0, stream>>>(
        himg, W_img2, b_img2, img, BATCH, DIM, HID);

    // fused logits + online softmax partials; then per-row LSE + mean
    logits_kernel<<<dim3(BATCH / LBN, BATCH / LBM), 256, 0, stream>>>(
        gout, label, img, pmax, psum, diagv);
    row_finalize_kernel<<<(BATCH * 64) / 256, 256, 0, stream>>>(pmax, psum, diagv, label, terms);
    final_sum_kernel<<<1, 256, 0, stream>>>(terms, (float*)d_out);
}

// Round 2
// 556.078 us; speedup vs baseline: 1.1922x; 1.1922x over previous
//
#include <hip/hip_runtime.h>
#include <hip/hip_bf16.h>
#include <math.h>

// Problem constants (fixed by the reference)
#define N_NODES 10000
#define N_EDGES 160000
#define BATCH   4096
#define DIM     512
#define HID     256
#define KEXT    1536   // 3 x 512: split-bf16 product expansion

typedef short short8 __attribute__((ext_vector_type(8)));
typedef float f32x4  __attribute__((ext_vector_type(4)));

// ---------------------------------------------------------------------------
// small utility kernels
// ---------------------------------------------------------------------------
__global__ void zero2_kernel(int* a, int* b, int n) {
    int i = blockIdx.x * blockDim.x + threadIdx.x;
    if (i < n) { a[i] = 0; b[i] = 0; }
}

__global__ void count_deg_kernel(const int* __restrict__ dst, int* __restrict__ cnt, int E) {
    int e = blockIdx.x * blockDim.x + threadIdx.x;
    if (e < E) atomicAdd(&cnt[dst[e]], 1);
}

__global__ void dinv_kernel(const int* __restrict__ cnt, float* __restrict__ dinv, int n) {
    int i = blockIdx.x * blockDim.x + threadIdx.x;
    if (i < n) dinv[i] = rsqrtf((float)(1 + cnt[i]));   // deg = 1 (self loop) + in-degree
}

// single-block exclusive scan of cnt[0..n) -> offs[0..n], offs[n] = total
__global__ void scan_offsets_kernel(const int* __restrict__ cnt, int* __restrict__ offs, int n) {
    __shared__ int buf[1024];
    __shared__ int base_s;
    if (threadIdx.x == 0) base_s = 0;
    __syncthreads();
    for (int start = 0; start < n; start += 1024) {
        int i = start + (int)threadIdx.x;
        int v = (i < n) ? cnt[i] : 0;
        buf[threadIdx.x] = v;
        __syncthreads();
        for (int off = 1; off < 1024; off <<= 1) {
            int add = (threadIdx.x >= (unsigned)off) ? buf[threadIdx.x - off] : 0;
            __syncthreads();
            buf[threadIdx.x] += add;
            __syncthreads();
        }
        if (i < n) offs[i] = base_s + buf[threadIdx.x] - v;   // exclusive
        __syncthreads();
        if (threadIdx.x == 0) base_s += buf[1023];
        __syncthreads();
    }
    if (threadIdx.x == 0) offs[n] = base_s;
}

__global__ void fill_csr_kernel(const int* __restrict__ dst, const int* __restrict__ offs,
                                int* __restrict__ cursor, int* __restrict__ csr, int E) {
    int e = blockIdx.x * blockDim.x + threadIdx.x;
    if (e < E) {
        int d = dst[e];
        int p = offs[d] + atomicAdd(&cursor[d], 1);
        csr[p] = e;
    }
}

// ---------------------------------------------------------------------------
// GCN aggregation
// ---------------------------------------------------------------------------
__global__ __launch_bounds__(256) void agg1_kernel(const float* __restrict__ xw,
        const float* __restrict__ dinv, const int* __restrict__ src,
        const int* __restrict__ offs, const int* __restrict__ csr,
        const float* __restrict__ bias, float* __restrict__ out) {
    int n = blockIdx.x;
    int c = threadIdx.x;          // 0..255
    float di = dinv[n];
    float acc = di * di * xw[(size_t)n * HID + c];
    int s0 = offs[n], s1 = offs[n + 1];
    for (int i = s0; i < s1; ++i) {
        int e  = csr[i];
        int sr = src[e];
        acc += di * dinv[sr] * xw[(size_t)sr * HID + c];
    }
    acc += bias[c];
    out[(size_t)n * HID + c] = fmaxf(acc, 0.0f);
}

__global__ __launch_bounds__(256) void agg2_kernel(const float* __restrict__ xw,
        const float* __restrict__ dinv, const int* __restrict__ src,
        const int* __restrict__ offs, const int* __restrict__ csr,
        const float* __restrict__ bias, float* __restrict__ out) {
    int n = blockIdx.x;
    int c = threadIdx.x;          // handles c and c+256
    float di = dinv[n];
    float d2 = di * di;
    float acc0 = d2 * xw[(size_t)n * DIM + c];
    float acc1 = d2 * xw[(size_t)n * DIM + c + 256];
    int s0 = offs[n], s1 = offs[n + 1];
    for (int i = s0; i < s1; ++i) {
        int e  = csr[i];
        int sr = src[e];
        float w = di * dinv[sr];
        acc0 += w * xw[(size_t)sr * DIM + c];
        acc1 += w * xw[(size_t)sr * DIM + c + 256];
    }
    out[(size_t)n * DIM + c]       = acc0 + bias[c];
    out[(size_t)n * DIM + c + 256] = acc1 + bias[c + 256];
}

// ---------------------------------------------------------------------------
// Dense NN GEMM: C[M,N] = A[M,K] @ B[K,N] (+bias, relu optional)  (fp32 VALU)
// ---------------------------------------------------------------------------
#define BM 128
#define BN 64
#define BK 16

template <bool BIAS_RELU>
__global__ __launch_bounds__(256) void gemm_nn_kernel(const float* __restrict__ A,
        const float* __restrict__ Bm, const float* __restrict__ bias,
        float* __restrict__ C, int M, int N, int K) {
    __shared__ float As[BK][BM + 4];
    __shared__ float Bs[BK][BN + 4];
    int t   = threadIdx.x;
    int rt  = blockIdx.y, ct = blockIdx.x;
    int row0 = rt * BM, col0 = ct * BN;
    int a_row = t >> 2;              // 0..63
    int a_k4  = (t & 3) * 4;         // 0,4,8,12
    int b_k   = t >> 4;              // 0..15
    int b_n   = (t & 15) * 4;        // 0..60
    int tx = t & 15, ty = t >> 4;

    float acc[8][4];
#pragma unroll
    for (int i = 0; i < 8; ++i)
#pragma unroll
        for (int j = 0; j < 4; ++j) acc[i][j] = 0.0f;

    for (int k0 = 0; k0 < K; k0 += BK) {
        int r1 = row0 + a_row;       if (r1 > M - 1) r1 = M - 1;
        int r2 = row0 + a_row + 64;  if (r2 > M - 1) r2 = M - 1;
        float4 v1 = *(const float4*)&A[(size_t)r1 * K + k0 + a_k4];
        float4 v2 = *(const float4*)&A[(size_t)r2 * K + k0 + a_k4];
        As[a_k4 + 0][a_row] = v1.x;  As[a_k4 + 1][a_row] = v1.y;
        As[a_k4 + 2][a_row] = v1.z;  As[a_k4 + 3][a_row] = v1.w;
        As[a_k4 + 0][a_row + 64] = v2.x;  As[a_k4 + 1][a_row + 64] = v2.y;
        As[a_k4 + 2][a_row + 64] = v2.z;  As[a_k4 + 3][a_row + 64] = v2.w;
        float4 bv = *(const float4*)&Bm[(size_t)(k0 + b_k) * N + col0 + b_n];
        *(float4*)&Bs[b_k][b_n] = bv;
        __syncthreads();
#pragma unroll
        for (int k = 0; k < BK; ++k) {
            float4 a0 = *(const float4*)&As[k][ty * 8];
            float4 a1 = *(const float4*)&As[k][ty * 8 + 4];
            float4 b0 = *(const float4*)&Bs[k][tx * 4];
            float av[8] = {a0.x, a0.y, a0.z, a0.w, a1.x, a1.y, a1.z, a1.w};
            float bvv[4] = {b0.x, b0.y, b0.z, b0.w};
#pragma unroll
            for (int i = 0; i < 8; ++i)
#pragma unroll
                for (int j = 0; j < 4; ++j) acc[i][j] = fmaf(av[i], bvv[j], acc[i][j]);
        }
        __syncthreads();
    }

    float4 bb = make_float4(0.f, 0.f, 0.f, 0.f);
    if (BIAS_RELU) bb = *(const float4*)&bias[col0 + tx * 4];
#pragma unroll
    for (int i = 0; i < 8; ++i) {
        int r = row0 + ty * 8 + i;
        if (r < M) {
            float4 v = make_float4(acc[i][0], acc[i][1], acc[i][2], acc[i][3]);
            if (BIAS_RELU) {
                v.x = fmaxf(v.x + bb.x, 0.f); v.y = fmaxf(v.y + bb.y, 0.f);
                v.z = fmaxf(v.z + bb.z, 0.f); v.w = fmaxf(v.w + bb.w, 0.f);
            }
            *(float4*)&C[(size_t)r * K + 0] = v;  // placeholder to silence unused warn (overwritten below)
            *(float4*)&C[(size_t)r * N + col0 + tx * 4] = v;
        }
    }
}

// ---------------------------------------------------------------------------
// split-bf16 helpers
// ---------------------------------------------------------------------------
__device__ __forceinline__ unsigned short f2bf(float x) {
    unsigned u = __float_as_uint(x);
    return (unsigned short)((u + 0x7FFFu + ((u >> 16) & 1u)) >> 16);   // RNE
}
__device__ __forceinline__ float bf2f(unsigned short h) {
    return __uint_as_float(((unsigned)h) << 16);
}

// Build K-extended bf16 matrices.
// MODE 0 (A/text, gathered by label): segments [hi | lo | hi]
// MODE 1 (B/image):                   segments [hi | hi | lo]
template <int MODE>
__global__ __launch_bounds__(256) void build_ext_kernel(const float* __restrict__ srcmat,
        const int* __restrict__ label, unsigned short* __restrict__ dstmat) {
    int id = blockIdx.x * 256 + threadIdx.x;     // BATCH*128 threads, 4 elems each
    int r  = id >> 7;
    int c4 = (id & 127) << 2;
    int srow = (MODE == 0) ? label[r] : r;
    float4 v = *(const float4*)&srcmat[(size_t)srow * DIM + c4];
    ushort4 h, l;
    h.x = f2bf(v.x); l.x = f2bf(v.x - bf2f(h.x));
    h.y = f2bf(v.y); l.y = f2bf(v.y - bf2f(h.y));
    h.z = f2bf(v.z); l.z = f2bf(v.z - bf2f(h.z));
    h.w = f2bf(v.w); l.w = f2bf(v.w - bf2f(h.w));
    unsigned short* base = dstmat + (size_t)r * KEXT;
    if (MODE == 0) {
        *(ushort4*)&base[c4]        = h;
        *(ushort4*)&base[512 + c4]  = l;
        *(ushort4*)&base[1024 + c4] = h;
    } else {
        *(ushort4*)&base[c4]        = h;
        *(ushort4*)&base[512 + c4]  = h;
        *(ushort4*)&base[1024 + c4] = l;
    }
}

// ---------------------------------------------------------------------------
// logits = Aext @ Bext^T  (bf16 MFMA, K=1536), fused online softmax partials.
// 128x128 tile, BK=32, 256 thr = 4 waves (2x2), each wave 64x64 via 4x4 16x16 tiles.
// LDS layout is fragment-order so global_load_lds staging AND ds_read_b128 are
// both stride-1 (conflict-free): chunk(r16, quad, m) at byte r16*1024+quad*256+m*16.
// ---------------------------------------------------------------------------
__device__ __forceinline__ void gld_lds16(const void* g, void* l) {
    __builtin_amdgcn_global_load_lds(
        (const __attribute__((address_space(1))) unsigned int*)g,
        (__attribute__((address_space(3))) unsigned int*)l, 16, 0, 0);
}

__global__ __launch_bounds__(256) void logits_mfma_kernel(
        const unsigned short* __restrict__ Aext, const unsigned short* __restrict__ Bext,
        float* __restrict__ pmax, float* __restrict__ psum, float* __restrict__ diagv) {
    __shared__ __align__(16) unsigned short sh[8192];   // 16 KB: A tile + B tile
    unsigned short* As = sh;                            // 4096 ushorts = 8 KB
    unsigned short* Bs = sh + 4096;

    int t    = threadIdx.x;
    int lane = t & 63;
    int w    = t >> 6;            // wave 0..3
    int wy   = w >> 1, wx = w & 1;
    int rt   = blockIdx.y, ct = blockIdx.x;
    int m    = lane & 15;         // row-within-16 / fragment row
    int q    = lane >> 4;         // quad: k-chunk for staging & frags

    // staging global pointers: lane (m,q) of wave w loads 16B of row r16*16+m at k-chunk q
    const unsigned short* ap0 = Aext + (size_t)(rt * 128 + w * 16 + m) * KEXT + q * 8;
    const unsigned short* ap1 = Aext + (size_t)(rt * 128 + (4 + w) * 16 + m) * KEXT + q * 8;
    const unsigned short* bp0 = Bext + (size_t)(ct * 128 + w * 16 + m) * KEXT + q * 8;
    const unsigned short* bp1 = Bext + (size_t)(ct * 128 + (4 + w) * 16 + m) * KEXT + q * 8;
    unsigned short* lA0 = As + w * 512;         // wave-uniform LDS bases (bytes: w*1024)
    unsigned short* lA1 = As + (4 + w) * 512;
    unsigned short* lB0 = Bs + w * 512;
    unsigned short* lB1 = Bs + (4 + w) * 512;

    f32x4 acc[4][4];
#pragma unroll
    for (int i = 0; i < 4; ++i)
#pragma unroll
        for (int j = 0; j < 4; ++j) acc[i][j] = (f32x4){0.f, 0.f, 0.f, 0.f};

    for (int k0 = 0; k0 < KEXT; k0 += 32) {
        gld_lds16(ap0, lA0);  gld_lds16(ap1, lA1);
        gld_lds16(bp0, lB0);  gld_lds16(bp1, lB1);
        ap0 += 32; ap1 += 32; bp0 += 32; bp1 += 32;
        __syncthreads();                         // drains vmcnt (global->LDS) per HIP semantics
        short8 af[4], bf[4];
#pragma unroll
        for (int i = 0; i < 4; ++i) af[i] = *(const short8*)&As[(wy * 4 + i) * 512 + lane * 8];
#pragma unroll
        for (int i = 0; i < 4; ++i) bf[i] = *(const short8*)&Bs[(wx * 4 + i) * 512 + lane * 8];
#pragma unroll
        for (int i = 0; i < 4; ++i)
#pragma unroll
            for (int j = 0; j < 4; ++j)
                acc[i][j] = __builtin_amdgcn_mfma_f32_16x16x32_bf16(af[i], bf[j], acc[i][j], 0, 0, 0);
        __syncthreads();
    }

    // C/D layout: col = lane&15, row = q*4 + reg  (within each 16x16 tile)
    // diag values
    if (rt == ct && wy == wx) {
        int reg = m - q * 4;
        if (reg >= 0 && reg < 4) {
#pragma unroll
            for (int mt = 0; mt < 4; ++mt) {
                float dv = (reg == 0) ? acc[mt][mt].x : (reg == 1) ? acc[mt][mt].y
                         : (reg == 2) ? acc[mt][mt].z : acc[mt][mt].w;
                diagv[rt * 128 + wy * 64 + mt * 16 + m] = dv;
            }
        }
    }

    // per-row online (max, sumexp) over this wave's 64 cols
#pragma unroll
    for (int mt = 0; mt < 4; ++mt) {
#pragma unroll
        for (int reg = 0; reg < 4; ++reg) {
            float v0 = (reg == 0) ? acc[mt][0].x : (reg == 1) ? acc[mt][0].y : (reg == 2) ? acc[mt][0].z : acc[mt][0].w;
            float v1 = (reg == 0) ? acc[mt][1].x : (reg == 1) ? acc[mt][1].y : (reg == 2) ? acc[mt][1].z : acc[mt][1].w;
            float v2 = (reg == 0) ? acc[mt][2].x : (reg == 1) ? acc[mt][2].y : (reg == 2) ? acc[mt][2].z : acc[mt][2].w;
            float v3 = (reg == 0) ? acc[mt][3].x : (reg == 1) ? acc[mt][3].y : (reg == 2) ? acc[mt][3].z : acc[mt][3].w;
            float mx = fmaxf(fmaxf(v0, v1), fmaxf(v2, v3));
            float sm = expf(v0 - mx) + expf(v1 - mx) + expf(v2 - mx) + expf(v3 - mx);
#pragma unroll
            for (int d = 1; d < 16; d <<= 1) {
                float mo = __shfl_xor(mx, d, 64);
                float so = __shfl_xor(sm, d, 64);
                float mn = fmaxf(mx, mo);
                sm = sm * expf(mx - mn) + so * expf(mo - mn);
                mx = mn;
            }
            if (m == 0) {
                int row = rt * 128 + wy * 64 + mt * 16 + q * 4 + reg;
                pmax[(size_t)row * 64 + ct * 2 + wx] = mx;
                psum[(size_t)row * 64 + ct * 2 + wx] = sm;
            }
        }
    }
}

// combine 64 col-tile partials per row -> per-row loss term
__global__ __launch_bounds__(256) void row_finalize_kernel(const float* __restrict__ pmax,
        const float* __restrict__ psum, const float* __restrict__ diagv,
        const int* __restrict__ label, float* __restrict__ terms) {
    int gid  = blockIdx.x * blockDim.x + threadIdx.x;
    int row  = gid >> 6;
    int lane = threadIdx.x & 63;
    if (row >= BATCH) return;
    float m = pmax[(size_t)row * 64 + lane];
    float s = psum[(size_t)row * 64 + lane];
#pragma unroll
    for (int d = 1; d < 64; d <<= 1) {
        float mo = __shfl_xor(m, d, 64);
        float so = __shfl_xor(s, d, 64);
        float mn = fmaxf(m, mo);
        s = s * expf(m - mn) + so * expf(mo - mn);
        m = mn;
    }
    if (lane == 0) {
        float lse = m + logf(s);
        terms[row] = -(float)label[row] * (diagv[row] - lse);
    }
}

__global__ __launch_bounds__(256) void final_sum_kernel(const float* __restrict__ terms,
                                                        float* __restrict__ out) {
    __shared__ float red[256];
    float s = 0.0f;
    for (int i = threadIdx.x; i < BATCH; i += 256) s += terms[i];
    red[threadIdx.x] = s;
    __syncthreads();
    for (int w = 128; w > 0; w >>= 1) {
        if (threadIdx.x < (unsigned)w) red[threadIdx.x] += red[threadIdx.x + w];
        __syncthreads();
    }
    // contrastive mean + triplet loss (identically 1.0: d_ap==d_an, relu(margin)=1)
    if (threadIdx.x == 0) out[0] = red[0] / (float)BATCH + 1.0f;
}

// ---------------------------------------------------------------------------
extern "C" void kernel_launch(void* const* d_in, const int* in_sizes, int n_in,
                              void* d_out, int out_size, void* d_ws, size_t ws_size,
                              hipStream_t stream) {
    const float* image   = (const float*)d_in[0];
    const float* x_nodes = (const float*)d_in[1];
    const int*   edge    = (const int*)d_in[2];
    const int*   label   = (const int*)d_in[3];
    const float* W_img1  = (const float*)d_in[4];
    const float* b_img1  = (const float*)d_in[5];
    const float* W_img2  = (const float*)d_in[6];
    const float* b_img2  = (const float*)d_in[7];
    const float* W_g1    = (const float*)d_in[8];
    const float* b_g1    = (const float*)d_in[9];
    const float* W_g2    = (const float*)d_in[10];
    const float* b_g2    = (const float*)d_in[11];
    const int* src = edge;              // edge_index[0]
    const int* dst = edge + N_EDGES;    // edge_index[1]

    // workspace carve-up (256B aligned regions)
    char* ws = (char*)d_ws;
    size_t off = 0;
    auto alloc = [&](size_t bytes) { size_t r = off; off = (off + bytes + 255) & ~(size_t)255; return r; };
    float* dinv   = (float*)(ws + alloc(N_NODES * 4));
    int*   cnt    = (int*)  (ws + alloc(N_NODES * 4));
    int*   offs   = (int*)  (ws + alloc((N_NODES + 1) * 4));
    int*   cursor = (int*)  (ws + alloc(N_NODES * 4));
    int*   csr    = (int*)  (ws + alloc(N_EDGES * 4));
    float* xw1    = (float*)(ws + alloc((size_t)N_NODES * HID * 4));
    float* h      = (float*)(ws + alloc((size_t)N_NODES * HID * 4));
    float* xw2    = (float*)(ws + alloc((size_t)N_NODES * DIM * 4));
    float* gout   = (float*)(ws + alloc((size_t)N_NODES * DIM * 4));
    float* himg   = (float*)(ws + alloc((size_t)BATCH * HID * 4));
    float* img    = (float*)(ws + alloc((size_t)BATCH * DIM * 4));
    unsigned short* Aext = (unsigned short*)(ws + alloc((size_t)BATCH * KEXT * 2));
    unsigned short* Bext = (unsigned short*)(ws + alloc((size_t)BATCH * KEXT * 2));
    float* pmax   = (float*)(ws + alloc((size_t)BATCH * 64 * 4));
    float* psum   = (float*)(ws + alloc((size_t)BATCH * 64 * 4));
    float* diagv  = (float*)(ws + alloc(BATCH * 4));
    float* terms  = (float*)(ws + alloc(BATCH * 4));

    // graph build: CSR by dst + symmetric-norm coefficients
    zero2_kernel<<<(N_NODES + 255) / 256, 256, 0, stream>>>(cnt, cursor, N_NODES);
    count_deg_kernel<<<(N_EDGES + 255) / 256, 256, 0, stream>>>(dst, cnt, N_EDGES);
    dinv_kernel<<<(N_NODES + 255) / 256, 256, 0, stream>>>(cnt, dinv, N_NODES);
    scan_offsets_kernel<<<1, 1024, 0, stream>>>(cnt, offs, N_NODES);
    fill_csr_kernel<<<(N_EDGES + 255) / 256, 256, 0, stream>>>(dst, offs, cursor, csr, N_EDGES);

    // GCN layer 1: xw1 = x_nodes @ W_g1 ; h = relu(agg + self + b)
    gemm_nn_kernel<false><<<dim3(HID / BN, (N_NODES + BM - 1) / BM), 256, 0, stream>>>(
        x_nodes, W_g1, nullptr, xw1, N_NODES, HID, DIM);
    agg1_kernel<<<N_NODES, 256, 0, stream>>>(xw1, dinv, src, offs, csr, b_g1, h);

    // GCN layer 2: xw2 = h @ W_g2 ; gout = agg + self + b
    gemm_nn_kernel<false><<<dim3(DIM / BN, (N_NODES + BM - 1) / BM), 256, 0, stream>>>(
        h, W_g2, nullptr, xw2, N_NODES, DIM, HID);
    agg2_kernel<<<N_NODES, 256, 0, stream>>>(xw2, dinv, src, offs, csr, b_g2, gout);

    // image MLP: himg = relu(image@W1+b1) ; img = relu(himg@W2+b2)
    gemm_nn_kernel<true><<<dim3(HID / BN, BATCH / BM), 256, 0, stream>>>(
        image, W_img1, b_img1, himg, BATCH, HID, DIM);
    gemm_nn_kernel<true><<<dim3(DIM / BN, BATCH / BM), 256, 0, stream>>>(
        himg, W_img2, b_img2, img, BATCH, DIM, HID);

    // split-bf16 K-extended operand build (A gathers gout[label])
    build_ext_kernel<0><<<(BATCH * 128) / 256, 256, 0, stream>>>(gout, label, Aext);
    build_ext_kernel<1><<<(BATCH * 128) / 256, 256, 0, stream>>>(img, label, Bext);

    // fused logits (bf16x3 MFMA) + online softmax partials; then per-row LSE + mean
    logits_mfma_kernel<<<dim3(BATCH / 128, BATCH / 128), 256, 0, stream>>>(
        Aext, Bext, pmax, psum, diagv);
    row_finalize_kernel<<<(BATCH * 64) / 256, 256, 0, stream>>>(pmax, psum, diagv, label, terms);
    final_sum_kernel<<<1, 256, 0, stream>>>(terms, (float*)d_out);
}

// Round 3
// 462.105 us; speedup vs baseline: 1.4346x; 1.2034x over previous
//
#include <hip/hip_runtime.h>
#include <hip/hip_bf16.h>
#include <math.h>

// Problem constants (fixed by the reference)
#define N_NODES 10000
#define N_EDGES 160000
#define BATCH   4096
#define DIM     512
#define HID     256
#define KEXT    1536   // 3 x 512: split-bf16 product expansion

typedef short short8 __attribute__((ext_vector_type(8)));
typedef float f32x4  __attribute__((ext_vector_type(4)));

// ---------------------------------------------------------------------------
// graph build utilities
// ---------------------------------------------------------------------------
__global__ void zero_init_kernel(int* cnt, int* cursor, int* flag, int* pcnt) {
    int i = blockIdx.x * blockDim.x + threadIdx.x;
    if (i < N_NODES) { cnt[i] = 0; cursor[i] = 0; flag[i] = 0; }
    if (i == 0) pcnt[0] = 0;
}

__global__ void count_deg_kernel(const int* __restrict__ dst, int* __restrict__ cnt) {
    int e = blockIdx.x * blockDim.x + threadIdx.x;
    if (e < N_EDGES) atomicAdd(&cnt[dst[e]], 1);
}

__global__ void mark_labels_kernel(const int* __restrict__ label, int* __restrict__ flag) {
    int b = blockIdx.x * blockDim.x + threadIdx.x;
    if (b < BATCH) flag[label[b]] = 1;          // idempotent, races benign
}

// block-local scan (256/block) + per-block sums; also computes dinv
__global__ __launch_bounds__(256) void scanA_kernel(const int* __restrict__ cnt,
        int* __restrict__ offs, int* __restrict__ bsum, float* __restrict__ dinv) {
    __shared__ int sh[256];
    int i = blockIdx.x * 256 + threadIdx.x;
    int v = (i < N_NODES) ? cnt[i] : 0;
    if (i < N_NODES) dinv[i] = rsqrtf((float)(1 + v));
    sh[threadIdx.x] = v;
    __syncthreads();
    for (int off = 1; off < 256; off <<= 1) {
        int t = (threadIdx.x >= (unsigned)off) ? sh[threadIdx.x - off] : 0;
        __syncthreads();
        sh[threadIdx.x] += t;
        __syncthreads();
    }
    if (i < N_NODES) offs[i] = sh[threadIdx.x] - v;   // exclusive within block
    if (threadIdx.x == 255) bsum[blockIdx.x] = sh[255];
}

__global__ void scanB_kernel(int* bsum, int nblocks) {
    if (threadIdx.x == 0 && blockIdx.x == 0) {
        int a = 0;
        for (int b = 0; b < nblocks; ++b) { int t = bsum[b]; bsum[b] = a; a += t; }
    }
}

__global__ __launch_bounds__(256) void scanC_kernel(int* __restrict__ offs,
                                                    const int* __restrict__ bsum) {
    int i = blockIdx.x * 256 + threadIdx.x;
    if (i < N_NODES) offs[i] += bsum[blockIdx.x];
    if (i == 0) offs[N_NODES] = N_EDGES;
}

__global__ void fill_csr_kernel(const int* __restrict__ dst, const int* __restrict__ offs,
                                int* __restrict__ cursor, int* __restrict__ csr) {
    int e = blockIdx.x * blockDim.x + threadIdx.x;
    if (e < N_EDGES) {
        int d = dst[e];
        int p = offs[d] + atomicAdd(&cursor[d], 1);
        csr[p] = e;
    }
}

__global__ void compact_kernel(const int* __restrict__ flag, int* __restrict__ pcnt,
                               int* __restrict__ nodelist, int* __restrict__ pos) {
    int n = blockIdx.x * blockDim.x + threadIdx.x;
    if (n < N_NODES && flag[n]) {
        int p = atomicAdd(pcnt, 1);
        nodelist[p] = n;
        pos[n] = p;
    }
}

// ---------------------------------------------------------------------------
// GCN aggregation over 256 channels: wave-per-node, float4 per lane.
// out[row] = sum_{e:dst=n} dinv[src]*dinv[n]*xw[src] + dinv[n]^2*xw[n] (+bias)(+relu)
// COMPACT: node ids from nodelist (count in pcnt), output row = compact slot.
// ---------------------------------------------------------------------------
template <int BIAS, int RELU, int COMPACT>
__global__ __launch_bounds__(256) void agg256_kernel(const float* __restrict__ xw,
        const float* __restrict__ dinv, const int* __restrict__ src,
        const int* __restrict__ offs, const int* __restrict__ csr,
        const float* __restrict__ bias, float* __restrict__ out,
        const int* __restrict__ nodelist, const int* __restrict__ pcnt) {
    int wid  = blockIdx.x * 4 + (threadIdx.x >> 6);
    int lane = threadIdx.x & 63;
    int n;
    if (COMPACT) { if (wid >= pcnt[0]) return; n = nodelist[wid]; }
    else         { if (wid >= N_NODES) return; n = wid; }
    int c4 = lane * 4;
    float di = dinv[n];
    float d2 = di * di;
    float4 self = *(const float4*)&xw[(size_t)n * 256 + c4];
    float4 a = make_float4(d2 * self.x, d2 * self.y, d2 * self.z, d2 * self.w);
    int s0 = offs[n], s1 = offs[n + 1];
    for (int i = s0; i < s1; ++i) {
        int e  = csr[i];
        int sr = src[e];
        float wgt = di * dinv[sr];
        float4 v = *(const float4*)&xw[(size_t)sr * 256 + c4];
        a.x = fmaf(wgt, v.x, a.x); a.y = fmaf(wgt, v.y, a.y);
        a.z = fmaf(wgt, v.z, a.z); a.w = fmaf(wgt, v.w, a.w);
    }
    if (BIAS) {
        float4 b = *(const float4*)&bias[c4];
        a.x += b.x; a.y += b.y; a.z += b.z; a.w += b.w;
    }
    if (RELU) {
        a.x = fmaxf(a.x, 0.f); a.y = fmaxf(a.y, 0.f);
        a.z = fmaxf(a.z, 0.f); a.w = fmaxf(a.w, 0.f);
    }
    int orow = COMPACT ? wid : n;
    *(float4*)&out[(size_t)orow * 256 + c4] = a;
}

// ---------------------------------------------------------------------------
// Dense NN GEMM: C[M,N] = A[M,K] @ B[K,N] (+bias)(+relu)  (fp32 VALU)
// tile 128x64, BK=16, 256 threads, 8x4 micro-tile per thread
// ---------------------------------------------------------------------------
#define BM 128
#define BN 64
#define BK 16

template <int BIAS, int RELU>
__global__ __launch_bounds__(256) void gemm_nn_kernel(const float* __restrict__ A,
        const float* __restrict__ Bm, const float* __restrict__ bias,
        float* __restrict__ C, int M, int N, int K) {
    __shared__ float As[BK][BM + 4];
    __shared__ float Bs[BK][BN + 4];
    int t   = threadIdx.x;
    int rt  = blockIdx.y, ct = blockIdx.x;
    int row0 = rt * BM, col0 = ct * BN;
    int a_row = t >> 2;              // 0..63
    int a_k4  = (t & 3) * 4;         // 0,4,8,12
    int b_k   = t >> 4;              // 0..15
    int b_n   = (t & 15) * 4;        // 0..60
    int tx = t & 15, ty = t >> 4;

    float acc[8][4];
#pragma unroll
    for (int i = 0; i < 8; ++i)
#pragma unroll
        for (int j = 0; j < 4; ++j) acc[i][j] = 0.0f;

    for (int k0 = 0; k0 < K; k0 += BK) {
        int r1 = row0 + a_row;       if (r1 > M - 1) r1 = M - 1;
        int r2 = row0 + a_row + 64;  if (r2 > M - 1) r2 = M - 1;
        float4 v1 = *(const float4*)&A[(size_t)r1 * K + k0 + a_k4];
        float4 v2 = *(const float4*)&A[(size_t)r2 * K + k0 + a_k4];
        As[a_k4 + 0][a_row] = v1.x;  As[a_k4 + 1][a_row] = v1.y;
        As[a_k4 + 2][a_row] = v1.z;  As[a_k4 + 3][a_row] = v1.w;
        As[a_k4 + 0][a_row + 64] = v2.x;  As[a_k4 + 1][a_row + 64] = v2.y;
        As[a_k4 + 2][a_row + 64] = v2.z;  As[a_k4 + 3][a_row + 64] = v2.w;
        float4 bv = *(const float4*)&Bm[(size_t)(k0 + b_k) * N + col0 + b_n];
        *(float4*)&Bs[b_k][b_n] = bv;
        __syncthreads();
#pragma unroll
        for (int k = 0; k < BK; ++k) {
            float4 a0 = *(const float4*)&As[k][ty * 8];
            float4 a1 = *(const float4*)&As[k][ty * 8 + 4];
            float4 b0 = *(const float4*)&Bs[k][tx * 4];
            float av[8] = {a0.x, a0.y, a0.z, a0.w, a1.x, a1.y, a1.z, a1.w};
            float bvv[4] = {b0.x, b0.y, b0.z, b0.w};
#pragma unroll
            for (int i = 0; i < 8; ++i)
#pragma unroll
                for (int j = 0; j < 4; ++j) acc[i][j] = fmaf(av[i], bvv[j], acc[i][j]);
        }
        __syncthreads();
    }

    float4 bb = make_float4(0.f, 0.f, 0.f, 0.f);
    if (BIAS) bb = *(const float4*)&bias[col0 + tx * 4];
#pragma unroll
    for (int i = 0; i < 8; ++i) {
        int r = row0 + ty * 8 + i;
        if (r < M) {
            float4 v = make_float4(acc[i][0] + bb.x, acc[i][1] + bb.y,
                                   acc[i][2] + bb.z, acc[i][3] + bb.w);
            if (RELU) {
                v.x = fmaxf(v.x, 0.f); v.y = fmaxf(v.y, 0.f);
                v.z = fmaxf(v.z, 0.f); v.w = fmaxf(v.w, 0.f);
            }
            *(float4*)&C[(size_t)r * N + col0 + tx * 4] = v;
        }
    }
}

// ---------------------------------------------------------------------------
// split-bf16 helpers
// ---------------------------------------------------------------------------
__device__ __forceinline__ unsigned short f2bf(float x) {
    unsigned u = __float_as_uint(x);
    return (unsigned short)((u + 0x7FFFu + ((u >> 16) & 1u)) >> 16);   // RNE
}
__device__ __forceinline__ float bf2f(unsigned short h) {
    return __uint_as_float(((unsigned)h) << 16);
}

// Build K-extended bf16 matrices (src row stride = DIM = 512).
// MODE 0 (A/text, gathered via pos[label[r]]): segments [hi | lo | hi]
// MODE 1 (B/image):                            segments [hi | hi | lo]
template <int MODE>
__global__ __launch_bounds__(256) void build_ext_kernel(const float* __restrict__ srcmat,
        const int* __restrict__ label, const int* __restrict__ pos,
        unsigned short* __restrict__ dstmat) {
    int id = blockIdx.x * 256 + threadIdx.x;     // BATCH*128 threads, 4 elems each
    int r  = id >> 7;
    int c4 = (id & 127) << 2;
    int srow = (MODE == 0) ? pos[label[r]] : r;
    float4 v = *(const float4*)&srcmat[(size_t)srow * DIM + c4];
    ushort4 h, l;
    h.x = f2bf(v.x); l.x = f2bf(v.x - bf2f(h.x));
    h.y = f2bf(v.y); l.y = f2bf(v.y - bf2f(h.y));
    h.z = f2bf(v.z); l.z = f2bf(v.z - bf2f(h.z));
    h.w = f2bf(v.w); l.w = f2bf(v.w - bf2f(h.w));
    unsigned short* base = dstmat + (size_t)r * KEXT;
    if (MODE == 0) {
        *(ushort4*)&base[c4]        = h;
        *(ushort4*)&base[512 + c4]  = l;
        *(ushort4*)&base[1024 + c4] = h;
    } else {
        *(ushort4*)&base[c4]        = h;
        *(ushort4*)&base[512 + c4]  = h;
        *(ushort4*)&base[1024 + c4] = l;
    }
}

// ---------------------------------------------------------------------------
// logits = Aext @ Bext^T  (bf16 MFMA, K=1536), fused online softmax partials.
// 128x128 tile, BK=32, 4 waves (2x2), wave = 64x64 via 4x4 16x16x32 MFMAs.
// LDS fragment-order layout (conflict-free ds_read_b128 + valid global_load_lds).
// Single barrier per K-step: double-buffered LDS, staging for step k+1 issued at
// top of step k and drained by the next barrier (one MFMA block of latency cover).
// ---------------------------------------------------------------------------
__device__ __forceinline__ void gld_lds16(const void* g, void* l) {
    __builtin_amdgcn_global_load_lds(
        (const __attribute__((address_space(1))) unsigned int*)g,
        (__attribute__((address_space(3))) unsigned int*)l, 16, 0, 0);
}

__global__ __launch_bounds__(256) void logits_mfma_kernel(
        const unsigned short* __restrict__ Aext, const unsigned short* __restrict__ Bext,
        float* __restrict__ pmax, float* __restrict__ psum, float* __restrict__ diagv) {
    __shared__ __align__(16) unsigned short sh[16384];   // 32 KB: 2 x (A 8KB + B 8KB)

    int t    = threadIdx.x;
    int lane = t & 63;
    int w    = t >> 6;            // wave 0..3
    int wy   = w >> 1, wx = w & 1;
    int rt   = blockIdx.y, ct = blockIdx.x;
    int m    = lane & 15;         // fragment row within 16
    int q    = lane >> 4;         // k-chunk quad

    // staging global pointers: lane (m,q) of wave w loads 16B of row (r16*16+m), k-chunk q
    const unsigned short* ap0 = Aext + (size_t)(rt * 128 + w * 16 + m) * KEXT + q * 8;
    const unsigned short* ap1 = ap0 + (size_t)64 * KEXT;
    const unsigned short* bp0 = Bext + (size_t)(ct * 128 + w * 16 + m) * KEXT + q * 8;
    const unsigned short* bp1 = bp0 + (size_t)64 * KEXT;

    f32x4 acc[4][4];
#pragma unroll
    for (int i = 0; i < 4; ++i)
#pragma unroll
        for (int j = 0; j < 4; ++j) acc[i][j] = (f32x4){0.f, 0.f, 0.f, 0.f};

    // prologue: stage k=0 into buffer 0
    {
        unsigned short* As = sh;
        unsigned short* Bs = sh + 4096;
        gld_lds16(ap0, As + w * 512);  gld_lds16(ap1, As + (4 + w) * 512);
        gld_lds16(bp0, Bs + w * 512);  gld_lds16(bp1, Bs + (4 + w) * 512);
    }

    const int NK = KEXT / 32;     // 48
    for (int k = 0; k < NK; ++k) {
        __syncthreads();          // drains vmcnt: buffer (k&1) staging complete
        // stage k+1 into the other buffer (in flight across this step's MFMAs)
        if (k + 1 < NK) {
            int koff = (k + 1) * 32;
            unsigned short* An = sh + ((k + 1) & 1) * 8192;
            unsigned short* Bn = An + 4096;
            gld_lds16(ap0 + koff, An + w * 512);  gld_lds16(ap1 + koff, An + (4 + w) * 512);
            gld_lds16(bp0 + koff, Bn + w * 512);  gld_lds16(bp1 + koff, Bn + (4 + w) * 512);
        }
        unsigned short* As = sh + (k & 1) * 8192;
        unsigned short* Bs = As + 4096;
        short8 af[4], bf[4];
#pragma unroll
        for (int i = 0; i < 4; ++i) af[i] = *(const short8*)&As[(wy * 4 + i) * 512 + lane * 8];
#pragma unroll
        for (int i = 0; i < 4; ++i) bf[i] = *(const short8*)&Bs[(wx * 4 + i) * 512 + lane * 8];
#pragma unroll
        for (int i = 0; i < 4; ++i)
#pragma unroll
            for (int j = 0; j < 4; ++j)
                acc[i][j] = __builtin_amdgcn_mfma_f32_16x16x32_bf16(af[i], bf[j], acc[i][j], 0, 0, 0);
    }

    // C/D layout: col = lane&15, row = q*4 + reg (within each 16x16 tile)
    // diagonal values
    if (rt == ct && wy == wx) {
        int reg = m - q * 4;
        if (reg >= 0 && reg < 4) {
#pragma unroll
            for (int mt = 0; mt < 4; ++mt) {
                f32x4 dvv = acc[mt][mt];
                float dv = (reg == 0) ? dvv.x : (reg == 1) ? dvv.y : (reg == 2) ? dvv.z : dvv.w;
                diagv[rt * 128 + wy * 64 + mt * 16 + m] = dv;
            }
        }
    }

    // per-row (max, sumexp) over this wave's 64 cols: max pass, then sum pass
#pragma unroll
    for (int mt = 0; mt < 4; ++mt) {
#pragma unroll
        for (int reg = 0; reg < 4; ++reg) {
            float v0 = acc[mt][0][reg], v1 = acc[mt][1][reg];
            float v2 = acc[mt][2][reg], v3 = acc[mt][3][reg];
            float mx = fmaxf(fmaxf(v0, v1), fmaxf(v2, v3));
#pragma unroll
            for (int d = 1; d < 16; d <<= 1) mx = fmaxf(mx, __shfl_xor(mx, d, 64));
            float sm = __expf(v0 - mx) + __expf(v1 - mx) + __expf(v2 - mx) + __expf(v3 - mx);
#pragma unroll
            for (int d = 1; d < 16; d <<= 1) sm += __shfl_xor(sm, d, 64);
            if (m == 0) {
                int row = rt * 128 + wy * 64 + mt * 16 + q * 4 + reg;
                pmax[(size_t)row * 64 + ct * 2 + wx] = mx;
                psum[(size_t)row * 64 + ct * 2 + wx] = sm;
            }
        }
    }
}

// combine 64 col-tile partials per row -> per-row loss term
__global__ __launch_bounds__(256) void row_finalize_kernel(const float* __restrict__ pmax,
        const float* __restrict__ psum, const float* __restrict__ diagv,
        const int* __restrict__ label, float* __restrict__ terms) {
    int gid  = blockIdx.x * blockDim.x + threadIdx.x;
    int row  = gid >> 6;
    int lane = threadIdx.x & 63;
    if (row >= BATCH) return;
    float m = pmax[(size_t)row * 64 + lane];
    float s = psum[(size_t)row * 64 + lane];
    float M = m;
#pragma unroll
    for (int d = 1; d < 64; d <<= 1) M = fmaxf(M, __shfl_xor(M, d, 64));
    s *= __expf(m - M);
#pragma unroll
    for (int d = 1; d < 64; d <<= 1) s += __shfl_xor(s, d, 64);
    if (lane == 0) {
        float lse = M + __logf(s);
        terms[row] = -(float)label[row] * (diagv[row] - lse);
    }
}

__global__ __launch_bounds__(256) void final_sum_kernel(const float* __restrict__ terms,
                                                        float* __restrict__ out) {
    __shared__ float red[256];
    float s = 0.0f;
    for (int i = threadIdx.x; i < BATCH; i += 256) s += terms[i];
    red[threadIdx.x] = s;
    __syncthreads();
    for (int w = 128; w > 0; w >>= 1) {
        if (threadIdx.x < (unsigned)w) red[threadIdx.x] += red[threadIdx.x + w];
        __syncthreads();
    }
    // contrastive mean + triplet loss (identically 1.0: d_ap==d_an, relu(margin)=1)
    if (threadIdx.x == 0) out[0] = red[0] / (float)BATCH + 1.0f;
}

// ---------------------------------------------------------------------------
extern "C" void kernel_launch(void* const* d_in, const int* in_sizes, int n_in,
                              void* d_out, int out_size, void* d_ws, size_t ws_size,
                              hipStream_t stream) {
    const float* image   = (const float*)d_in[0];
    const float* x_nodes = (const float*)d_in[1];
    const int*   edge    = (const int*)d_in[2];
    const int*   label   = (const int*)d_in[3];
    const float* W_img1  = (const float*)d_in[4];
    const float* b_img1  = (const float*)d_in[5];
    const float* W_img2  = (const float*)d_in[6];
    const float* b_img2  = (const float*)d_in[7];
    const float* W_g1    = (const float*)d_in[8];
    const float* b_g1    = (const float*)d_in[9];
    const float* W_g2    = (const float*)d_in[10];
    const float* b_g2    = (const float*)d_in[11];
    const int* src = edge;              // edge_index[0]
    const int* dst = edge + N_EDGES;    // edge_index[1]

    // workspace carve-up (256B aligned regions)
    char* ws = (char*)d_ws;
    size_t off = 0;
    auto alloc = [&](size_t bytes) { size_t r = off; off = (off + bytes + 255) & ~(size_t)255; return r; };
    float* dinv     = (float*)(ws + alloc(N_NODES * 4));
    int*   cnt      = (int*)  (ws + alloc(N_NODES * 4));
    int*   offs     = (int*)  (ws + alloc((N_NODES + 1) * 4));
    int*   cursor   = (int*)  (ws + alloc(N_NODES * 4));
    int*   csr      = (int*)  (ws + alloc(N_EDGES * 4));
    int*   flag     = (int*)  (ws + alloc(N_NODES * 4));
    int*   pos      = (int*)  (ws + alloc(N_NODES * 4));
    int*   nodelist = (int*)  (ws + alloc(BATCH * 4));
    int*   pcnt     = (int*)  (ws + alloc(4));
    int*   bsum     = (int*)  (ws + alloc(64 * 4));
    float* xw1    = (float*)(ws + alloc((size_t)N_NODES * HID * 4));
    float* h      = (float*)(ws + alloc((size_t)N_NODES * HID * 4));
    float* g2in   = (float*)(ws + alloc((size_t)BATCH * HID * 4));    // (A-hat h) on compact rows
    float* g2out  = (float*)(ws + alloc((size_t)BATCH * DIM * 4));    // compact gout rows
    float* himg   = (float*)(ws + alloc((size_t)BATCH * HID * 4));
    float* img    = (float*)(ws + alloc((size_t)BATCH * DIM * 4));
    unsigned short* Aext = (unsigned short*)(ws + alloc((size_t)BATCH * KEXT * 2));
    unsigned short* Bext = (unsigned short*)(ws + alloc((size_t)BATCH * KEXT * 2));
    float* pmax   = (float*)(ws + alloc((size_t)BATCH * 64 * 4));
    float* psum   = (float*)(ws + alloc((size_t)BATCH * 64 * 4));
    float* diagv  = (float*)(ws + alloc(BATCH * 4));
    float* terms  = (float*)(ws + alloc(BATCH * 4));

    const int SCAN_BLOCKS = (N_NODES + 255) / 256;   // 40

    // graph build: CSR by dst + symmetric-norm coefficients + label compaction
    zero_init_kernel<<<SCAN_BLOCKS, 256, 0, stream>>>(cnt, cursor, flag, pcnt);
    count_deg_kernel<<<(N_EDGES + 255) / 256, 256, 0, stream>>>(dst, cnt);
    mark_labels_kernel<<<(BATCH + 255) / 256, 256, 0, stream>>>(label, flag);
    scanA_kernel<<<SCAN_BLOCKS, 256, 0, stream>>>(cnt, offs, bsum, dinv);
    scanB_kernel<<<1, 64, 0, stream>>>(bsum, SCAN_BLOCKS);
    scanC_kernel<<<SCAN_BLOCKS, 256, 0, stream>>>(offs, bsum);
    fill_csr_kernel<<<(N_EDGES + 255) / 256, 256, 0, stream>>>(dst, offs, cursor, csr);
    compact_kernel<<<SCAN_BLOCKS, 256, 0, stream>>>(flag, pcnt, nodelist, pos);

    // GCN layer 1: xw1 = x_nodes @ W_g1 ; h = relu(A-hat xw1 + b1)
    gemm_nn_kernel<0, 0><<<dim3(HID / BN, (N_NODES + BM - 1) / BM), 256, 0, stream>>>(
        x_nodes, W_g1, nullptr, xw1, N_NODES, HID, DIM);
    agg256_kernel<1, 1, 0><<<(N_NODES + 3) / 4, 256, 0, stream>>>(
        xw1, dinv, src, offs, csr, b_g1, h, nullptr, nullptr);

    // GCN layer 2 (reordered, compact): g2in = A-hat h (label rows only);
    // g2out = g2in @ W_g2 + b2
    agg256_kernel<0, 0, 1><<<BATCH / 4, 256, 0, stream>>>(
        h, dinv, src, offs, csr, nullptr, g2in, nodelist, pcnt);
    gemm_nn_kernel<1, 0><<<dim3(DIM / BN, BATCH / BM), 256, 0, stream>>>(
        g2in, W_g2, b_g2, g2out, BATCH, DIM, HID);

    // image MLP: himg = relu(image@W1+b1) ; img = relu(himg@W2+b2)
    gemm_nn_kernel<1, 1><<<dim3(HID / BN, BATCH / BM), 256, 0, stream>>>(
        image, W_img1, b_img1, himg, BATCH, HID, DIM);
    gemm_nn_kernel<1, 1><<<dim3(DIM / BN, BATCH / BM), 256, 0, stream>>>(
        himg, W_img2, b_img2, img, BATCH, DIM, HID);

    // split-bf16 K-extended operand build (A gathers compact gout rows via pos[label])
    build_ext_kernel<0><<<(BATCH * 128) / 256, 256, 0, stream>>>(g2out, label, pos, Aext);
    build_ext_kernel<1><<<(BATCH * 128) / 256, 256, 0, stream>>>(img, label, pos, Bext);

    // fused logits (bf16x3 MFMA) + online softmax partials; then per-row LSE + mean
    logits_mfma_kernel<<<dim3(BATCH / 128, BATCH / 128), 256, 0, stream>>>(
        Aext, Bext, pmax, psum, diagv);
    row_finalize_kernel<<<(BATCH * 64) / 256, 256, 0, stream>>>(pmax, psum, diagv, label, terms);
    final_sum_kernel<<<1, 256, 0, stream>>>(terms, (float*)d_out);
}